// Round 12
// baseline (61297.180 us; speedup 1.0000x reference)
//
#include <hip/hip_runtime.h>
#include <hip/hip_bf16.h>
#include <hip/hip_cooperative_groups.h>
#include <math.h>

namespace cg = cooperative_groups;

typedef unsigned short u16;
typedef short short8v __attribute__((ext_vector_type(8)));
typedef float f32x4 __attribute__((ext_vector_type(4)));

#define TT 512
#define BB 128
#define IND 259
#define KPWF 384

// gemm_p (M=128,NC=64,BK=32): per buffer A_hi[128][80] A_lo + B_hi[64][80] B_lo
#define P_APL 10240
#define P_BPL 5120
#define P_BUF 30720
#define LDS_P 61440
// gemm_h (M=64,NC=64,BK=32): 2*(2*5120+2*5120) = 40960
#define H_APL 5120
#define H_BPL 5120
#define H_BUF 20480
#define LDS_H 40960

__device__ __forceinline__ u16 f2bf(float x) {
    __hip_bfloat16 h = __float2bfloat16(x);
    return *reinterpret_cast<u16*>(&h);
}
__device__ __forceinline__ float bf2f(u16 u) {
    unsigned v = ((unsigned)u) << 16;
    return __uint_as_float(v);
}
__device__ __forceinline__ void splitbf(float x, u16& hi, u16& lo) {
    hi = f2bf(x);
    lo = f2bf(x - bf2f(hi));
}
__device__ __forceinline__ float sigm(float x) { return 1.f / (1.f + expf(-x)); }

// ---------------- small prep kernels ----------------
__global__ __launch_bounds__(256) void k_zero(float* __restrict__ p, int n) {
    int i = blockIdx.x * 256 + threadIdx.x;
    int stride = gridDim.x * 256;
    for (; i < n; i += stride) p[i] = 0.f;
}

__global__ __launch_bounds__(256) void k_fold(const float* __restrict__ embW,
                                              const float* __restrict__ W0,
                                              float* __restrict__ WF) {
    int j = blockIdx.x * 256 + threadIdx.x;
    int i = blockIdx.y;
    float acc = 0.f;
    for (int e = 0; e < 512; ++e)
        acc += embW[i * 512 + e] * W0[(size_t)e * 4096 + j];
    WF[(size_t)i * 4096 + j] = acc;
}

__global__ __launch_bounds__(256) void k_S(const float* __restrict__ W0, float* __restrict__ S) {
    int j = blockIdx.x * 256 + threadIdx.x;
    float acc = 0.f;
    for (int r = 0; r < 128; ++r)
        acc += W0[(size_t)(512 + r) * 4096 + j];
    S[j] = acc;
}

__global__ __launch_bounds__(256) void k_sgn(const float* __restrict__ inp, float* __restrict__ sgn) {
    int i = blockIdx.x * 256 + threadIdx.x;
    float f0 = inp[(size_t)i * IND + 256];
    float f1 = inp[(size_t)i * IND + 257];
    sgn[i] = (f0 == 1.0f && f1 == 0.0f) ? 1.0f : -1.0f;
}

__global__ __launch_bounds__(256) void k_split(const float* __restrict__ src, int srcStride,
                                               int K, int Kpad, int perm,
                                               u16* __restrict__ hi, u16* __restrict__ lo) {
    int col = blockIdx.y;
    int k = blockIdx.x * 256 + threadIdx.x;
    if (k >= Kpad) return;
    int j = col;
    if (perm) {
        int c = col & 15, g = (col >> 4) & 3, hs = col >> 6;
        j = g * 1024 + hs * 16 + c;
    }
    float v = (k < K) ? src[(size_t)k * srcStride + j] : 0.f;
    u16 h, l; splitbf(v, h, l);
    hi[(size_t)col * Kpad + k] = h;
    lo[(size_t)col * Kpad + k] = l;
}

// ================= phase-A core: M=128 x NC=64, BK=32, 4 waves =================
template<int AMODE>
__device__ __forceinline__ void gemm_p(
    char* smem, int tid,
    const u16* Ah, const u16* Al, int lda,
    const float* Af, int kmax,
    const u16* Bh, const u16* Bl, int ldb,
    int ntiles,
    f32x4 (&acc)[4][2])
{
    const int lane = tid & 63, wid = tid >> 6;
    const int wrg = wid >> 1, wcg = wid & 1;
    const int rlo = lane & 15, khi = lane >> 4;
    const int srow = tid >> 1;          // 0..127
    const int sk   = (tid & 1) * 16;    // 16 elems per thread per plane
    const int bcol = tid >> 2;          // 0..63
    const int bs   = tid & 3;
    const int bplane = bs >> 1, bq = bs & 1;

    uint4 ra0, ra1, rl0, rl1, rb0, rb1;
    float rf[16];

    auto LOADF = [&](int tile) {
        if constexpr (AMODE == 0) {
            const u16* pa = Ah + (size_t)srow * lda + tile * 32 + sk;
            ra0 = *(const uint4*)(pa);
            ra1 = *(const uint4*)(pa + 8);
            const u16* pl = Al + (size_t)srow * lda + tile * 32 + sk;
            rl0 = *(const uint4*)(pl);
            rl1 = *(const uint4*)(pl + 8);
        } else {
            const float* sa = Af + (size_t)srow * lda;
            int k0 = tile * 32 + sk;
            #pragma unroll
            for (int j = 0; j < 16; ++j) rf[j] = (k0 + j < kmax) ? sa[k0 + j] : 0.f;
        }
        const u16* bp = bplane ? Bl : Bh;
        const u16* s = bp + (size_t)bcol * ldb + tile * 32 + bq * 16;
        rb0 = *(const uint4*)(s);
        rb1 = *(const uint4*)(s + 8);
    };
    auto WRITEF = [&](int tile) {
        char* buf = smem + (tile & 1) * P_BUF;
        char* d = buf + srow * 80 + sk * 2;
        if constexpr (AMODE == 0) {
            *(uint4*)d = ra0;
            *(uint4*)(d + 16) = ra1;
            *(uint4*)(d + P_APL) = rl0;
            *(uint4*)(d + P_APL + 16) = rl1;
        } else {
            alignas(16) u16 hb[16], lb[16];
            #pragma unroll
            for (int j = 0; j < 16; ++j) splitbf(rf[j], hb[j], lb[j]);
            *(uint4*)d = *(const uint4*)hb;
            *(uint4*)(d + 16) = *(const uint4*)(hb + 8);
            *(uint4*)(d + P_APL) = *(const uint4*)lb;
            *(uint4*)(d + P_APL + 16) = *(const uint4*)(lb + 8);
        }
        char* e = buf + 2 * P_APL + bplane * P_BPL + bcol * 80 + bq * 32;
        *(uint4*)(e) = rb0;
        *(uint4*)(e + 16) = rb1;
    };
    auto COMPUTEF = [&](int kt) {
        const char* buf = smem + (kt & 1) * P_BUF;
        short8v ah[4], al[4], bh[2], bl[2];
        #pragma unroll
        for (int rfi = 0; rfi < 4; ++rfi) {
            int row = wrg * 64 + rfi * 16 + rlo;
            const char* p = buf + row * 80 + khi * 16;
            ah[rfi] = *(const short8v*)p;
            al[rfi] = *(const short8v*)(p + P_APL);
        }
        #pragma unroll
        for (int cfi = 0; cfi < 2; ++cfi) {
            int col = wcg * 32 + cfi * 16 + rlo;
            const char* q = buf + 2 * P_APL + col * 80 + khi * 16;
            bh[cfi] = *(const short8v*)q;
            bl[cfi] = *(const short8v*)(q + P_BPL);
        }
        #pragma unroll
        for (int rfi = 0; rfi < 4; ++rfi)
            #pragma unroll
            for (int cfi = 0; cfi < 2; ++cfi) {
                acc[rfi][cfi] = __builtin_amdgcn_mfma_f32_16x16x32_bf16(ah[rfi], bh[cfi], acc[rfi][cfi], 0, 0, 0);
                acc[rfi][cfi] = __builtin_amdgcn_mfma_f32_16x16x32_bf16(ah[rfi], bl[cfi], acc[rfi][cfi], 0, 0, 0);
                acc[rfi][cfi] = __builtin_amdgcn_mfma_f32_16x16x32_bf16(al[rfi], bh[cfi], acc[rfi][cfi], 0, 0, 0);
            }
    };

    LOADF(0); WRITEF(0); __syncthreads();
    for (int kt = 0; kt < ntiles; ++kt) {
        if (kt + 1 < ntiles) LOADF(kt + 1);
        COMPUTEF(kt);
        if (kt + 1 < ntiles) WRITEF(kt + 1);
        __syncthreads();
    }
}

__device__ __forceinline__ void store_acc_p(float* __restrict__ out, int col0, int tid,
                                            f32x4 (&acc)[4][2]) {
    const int lane = tid & 63, wid = tid >> 6;
    const int wrg = wid >> 1, wcg = wid & 1;
    const int rlo = lane & 15, khi = lane >> 4;
    #pragma unroll
    for (int rfi = 0; rfi < 4; ++rfi)
        #pragma unroll
        for (int cfi = 0; cfi < 2; ++cfi)
            #pragma unroll
            for (int r = 0; r < 4; ++r)
                out[(size_t)(wrg*64 + rfi*16 + khi*4 + r) * 4096 + col0 + wcg*32 + cfi*16 + rlo] = acc[rfi][cfi][r];
}

// ---------------- shared args ----------------
struct PArgs {
    const float *inp, *Sv, *SG, *b0, *b1, *ob0, *ob1;
    const u16 *WFh, *WFl, *W0h, *W0l, *W1h, *W1l;
    const u16 *oWAh, *oWAl, *oWBh, *oWBl;
    u16 *h0h0, *h0l0, *h0h1, *h0l1, *ringh, *ringl, *hsh, *hsl;
    float *P0, *P1, *Zin, *c0, *c1;
    float* out;
    int R;
};

// ---------------- phase A task (448 tasks) ----------------
__device__ void phaseA_task(char* smem, int tid, int task, int L, const PArgs& a) {
    f32x4 acc[4][2];
    #pragma unroll
    for (int i = 0; i < 4; ++i) { acc[i][0] = (f32x4)0.f; acc[i][1] = (f32x4)0.f; }
    if (task < 128) {
        if (L < 0 || L >= TT) return;
        const int cb = task >> 1, s = task & 1;
        const u16* Ah = (((L - 1) & 1) ? a.h0h1 : a.h0h0) + s * 512;
        const u16* Al = (((L - 1) & 1) ? a.h0l1 : a.h0l0) + s * 512;
        gemm_p<0>(smem, tid, Ah, Al, 1024, nullptr, 0,
                  a.W0h + (size_t)(cb * 64) * 1024 + s * 512,
                  a.W0l + (size_t)(cb * 64) * 1024 + s * 512, 1024, 16, acc);
        store_acc_p(a.P0 + (size_t)s * BB * 4096, cb * 64, tid, acc);
    } else if (task < 384) {
        const int tau = L - 1;
        if (tau < 0 || tau >= TT) return;
        const int q = task - 128, cb = q >> 2, s = q & 3;
        const u16 *Ah, *Al;
        if (s < 2) {
            Ah = (((tau & 1) ? a.h0h1 : a.h0h0)) + s * 512;
            Al = (((tau & 1) ? a.h0l1 : a.h0l0)) + s * 512;
        } else {
            int slot = (tau - 1 + a.R) % a.R;
            Ah = a.ringh + (size_t)slot * BB * 1024 + (s - 2) * 512;
            Al = a.ringl + (size_t)slot * BB * 1024 + (s - 2) * 512;
        }
        gemm_p<0>(smem, tid, Ah, Al, 1024, nullptr, 0,
                  a.W1h + (size_t)(cb * 64) * 2048 + s * 512,
                  a.W1l + (size_t)(cb * 64) * 2048 + s * 512, 2048, 16, acc);
        store_acc_p(a.P1 + (size_t)s * BB * 4096, cb * 64, tid, acc);
    } else {
        const int tz = L + 1;
        if (tz < 0 || tz >= TT) return;
        const int cb = task - 384;
        gemm_p<1>(smem, tid, nullptr, nullptr, IND,
                  a.inp + (size_t)tz * BB * IND, IND,
                  a.WFh + (size_t)(cb * 64) * KPWF,
                  a.WFl + (size_t)(cb * 64) * KPWF, KPWF, 12, acc);
        store_acc_p(a.Zin + (size_t)(tz & 1) * BB * 4096, cb * 64, tid, acc);
    }
}

// ---------------- gate combine [R10-proven] ----------------
template<int NS, bool CELL0>
__device__ __forceinline__ void gate_work(
    const float* __restrict__ Pb, const float* __restrict__ zin,
    float sg, const float* __restrict__ Sv, const float* __restrict__ bias,
    float* __restrict__ cst, u16* __restrict__ oh, u16* __restrict__ ol,
    int row, int hs)
{
    float z[4][16];
    #pragma unroll
    for (int g = 0; g < 4; ++g) {
        #pragma unroll
        for (int c4 = 0; c4 < 4; ++c4) {
            float4 v = make_float4(0.f, 0.f, 0.f, 0.f);
            #pragma unroll
            for (int s = 0; s < NS; ++s) {
                float4 p = *(const float4*)(Pb + (size_t)s * BB * 4096 + g * 16 + c4 * 4);
                v.x += p.x; v.y += p.y; v.z += p.z; v.w += p.w;
            }
            if (CELL0) {
                float4 p = *(const float4*)(zin + g * 16 + c4 * 4);
                v.x += p.x; v.y += p.y; v.z += p.z; v.w += p.w;
                float4 sv = *(const float4*)(Sv + g * 1024 + hs * 16 + c4 * 4);
                v.x += sg * sv.x; v.y += sg * sv.y; v.z += sg * sv.z; v.w += sg * sv.w;
            }
            float4 bv = *(const float4*)(bias + g * 1024 + hs * 16 + c4 * 4);
            v.x += bv.x; v.y += bv.y; v.z += bv.z; v.w += bv.w;
            z[g][c4*4+0] = v.x; z[g][c4*4+1] = v.y; z[g][c4*4+2] = v.z; z[g][c4*4+3] = v.w;
        }
    }
    alignas(16) u16 hh[16], hl[16];
    float* cp = cst + (size_t)row * 1024 + hs * 16;
    #pragma unroll
    for (int c4 = 0; c4 < 4; ++c4) {
        float4 cv = *(const float4*)(cp + c4 * 4);
        float cc[4] = {cv.x, cv.y, cv.z, cv.w};
        #pragma unroll
        for (int e = 0; e < 4; ++e) {
            int c = c4 * 4 + e;
            float F = sigm(z[0][c]);
            float I = sigm(z[1][c]);
            float O = sigm(z[2][c]);
            float G = tanhf(z[3][c]);
            float cn = F * cc[e] + I * G;
            cc[e] = cn;
            float h = O * tanhf(cn);
            splitbf(h, hh[c], hl[c]);
        }
        *(float4*)(cp + c4 * 4) = make_float4(cc[0], cc[1], cc[2], cc[3]);
    }
    u16* ph = oh + (size_t)row * 1024 + hs * 16;
    u16* pl = ol + (size_t)row * 1024 + hs * 16;
    *(uint4*)(ph) = *(const uint4*)(hh);
    *(uint4*)(ph + 8) = *(const uint4*)(hh + 8);
    *(uint4*)(pl) = *(const uint4*)(hl);
    *(uint4*)(pl + 8) = *(const uint4*)(hl + 8);
}

__device__ void phaseB_item(int g, int L, const PArgs& a) {
    if (g < 8192) {
        if (L < 0 || L >= TT) return;
        int row = g >> 6, hs = g & 63;
        const float* Pb = a.P0 + (size_t)row * 4096 + hs * 64;
        const float* zin = a.Zin + (size_t)(L & 1) * BB * 4096 + (size_t)row * 4096 + hs * 64;
        float sg = a.SG[(size_t)L * BB + row];
        u16* oh = (L & 1) ? a.h0h1 : a.h0h0;
        u16* ol = (L & 1) ? a.h0l1 : a.h0l0;
        gate_work<2, true>(Pb, zin, sg, a.Sv, a.b0, a.c0, oh, ol, row, hs);
    } else if (g < 16384) {
        const int tau = L - 1;
        if (tau < 0 || tau >= TT) return;
        int g2 = g - 8192;
        int row = g2 >> 6, hs = g2 & 63;
        const float* Pb = a.P1 + (size_t)row * 4096 + hs * 64;
        int slot = tau % a.R;
        u16* oh = a.ringh + (size_t)slot * BB * 1024;
        u16* ol = a.ringl + (size_t)slot * BB * 1024;
        gate_work<4, false>(Pb, nullptr, 0.f, nullptr, a.b1, a.c1, oh, ol, row, hs);
    }
}

// ================= head core: M=64 x NC=64, BK=32 [R6-proven] =================
__device__ __forceinline__ void gemm_h(
    char* smem, int tid,
    const u16* Ah0, const u16* Al0,
    const u16* Bh, const u16* Bl, int ldb,
    int nkt,
    f32x4 (&acc)[2][2])
{
    const int lane = tid & 63, wid = tid >> 6;
    const int wrg = wid >> 1, wcg = wid & 1;
    const int rlo = lane & 15, khi = lane >> 4;
    const int srow = tid >> 2;
    const int sk8  = (tid & 3) * 8;
    const int bcol = tid >> 2;
    const int bs = tid & 3;
    const int bplane = bs >> 1, bq = bs & 1;

    uint4 ra0, ra1, rb0, rb1;

    auto LOADF = [&](int tile) {
        int k0 = tile * 32;
        ra0 = *(const uint4*)(Ah0 + (size_t)srow * 1024 + k0 + sk8);
        ra1 = *(const uint4*)(Al0 + (size_t)srow * 1024 + k0 + sk8);
        const u16* bp = bplane ? Bl : Bh;
        const u16* s = bp + (size_t)bcol * ldb + k0 + bq * 16;
        rb0 = *(const uint4*)(s);
        rb1 = *(const uint4*)(s + 8);
    };
    auto WRITEF = [&](int tile) {
        char* buf = smem + (tile & 1) * H_BUF;
        char* d = buf + srow * 80 + sk8 * 2;
        *(uint4*)d = ra0;
        *(uint4*)(d + H_APL) = ra1;
        char* e = buf + 2 * H_APL + bplane * H_BPL + bcol * 80;
        *(uint4*)(e + bq * 32) = rb0;
        *(uint4*)(e + bq * 32 + 16) = rb1;
    };
    auto COMPUTEF = [&](int kt) {
        const char* buf = smem + (kt & 1) * H_BUF;
        short8v ah[2], al[2], bh[2], bl[2];
        #pragma unroll
        for (int rfi = 0; rfi < 2; ++rfi) {
            int row = wrg * 32 + rfi * 16 + rlo;
            const char* p = buf + row * 80 + khi * 16;
            ah[rfi] = *(const short8v*)p;
            al[rfi] = *(const short8v*)(p + H_APL);
        }
        #pragma unroll
        for (int cfi = 0; cfi < 2; ++cfi) {
            int col = wcg * 32 + cfi * 16 + rlo;
            const char* q = buf + 2 * H_APL + col * 80 + khi * 16;
            bh[cfi] = *(const short8v*)q;
            bl[cfi] = *(const short8v*)(q + H_BPL);
        }
        #pragma unroll
        for (int rfi = 0; rfi < 2; ++rfi)
            #pragma unroll
            for (int cfi = 0; cfi < 2; ++cfi) {
                acc[rfi][cfi] = __builtin_amdgcn_mfma_f32_16x16x32_bf16(ah[rfi], bh[cfi], acc[rfi][cfi], 0, 0, 0);
                acc[rfi][cfi] = __builtin_amdgcn_mfma_f32_16x16x32_bf16(ah[rfi], bl[cfi], acc[rfi][cfi], 0, 0, 0);
                acc[rfi][cfi] = __builtin_amdgcn_mfma_f32_16x16x32_bf16(al[rfi], bh[cfi], acc[rfi][cfi], 0, 0, 0);
            }
    };

    LOADF(0); WRITEF(0); __syncthreads();
    for (int kt = 0; kt < nkt; ++kt) {
        if (kt + 1 < nkt) LOADF(kt + 1);
        COMPUTEF(kt);
        if (kt + 1 < nkt) WRITEF(kt + 1);
        __syncthreads();
    }
}

__device__ void head1_work(char* smem, int tid, int mb, int nb, const PArgs& a) {
    const size_t m0 = (size_t)mb * 64;
    f32x4 acc[2][2];
    #pragma unroll
    for (int i = 0; i < 2; ++i) { acc[i][0] = (f32x4)0.f; acc[i][1] = (f32x4)0.f; }
    gemm_h(smem, tid, a.ringh + m0 * 1024, a.ringl + m0 * 1024,
           a.oWAh + (size_t)nb*64*1024, a.oWAl + (size_t)nb*64*1024, 1024, 32, acc);
    const int lane = tid & 63, wid = tid >> 6;
    const int wrg = wid >> 1, wcg = wid & 1;
    const int rlo = lane & 15, khi = lane >> 4;
    #pragma unroll
    for (int rfi = 0; rfi < 2; ++rfi)
        #pragma unroll
        for (int cfi = 0; cfi < 2; ++cfi)
            #pragma unroll
            for (int r = 0; r < 4; ++r) {
                int row = wrg*32 + rfi*16 + khi*4 + r;
                int col = nb*64 + wcg*32 + cfi*16 + rlo;
                float v = acc[rfi][cfi][r] + a.ob0[col];
                v = fmaxf(v, 0.f);
                u16 hh, hl; splitbf(v, hh, hl);
                size_t o = (m0 + row) * 1024 + col;
                a.hsh[o] = hh; a.hsl[o] = hl;
            }
}

__device__ void head2_work(char* smem, int tid, int mb, int nb, const PArgs& a, float* outp) {
    const size_t m0 = (size_t)mb * 64;
    f32x4 acc[2][2];
    #pragma unroll
    for (int i = 0; i < 2; ++i) { acc[i][0] = (f32x4)0.f; acc[i][1] = (f32x4)0.f; }
    gemm_h(smem, tid, a.hsh + m0 * 1024, a.hsl + m0 * 1024,
           a.oWBh + (size_t)nb*64*1024, a.oWBl + (size_t)nb*64*1024, 1024, 32, acc);
    const int lane = tid & 63, wid = tid >> 6;
    const int wrg = wid >> 1, wcg = wid & 1;
    const int rlo = lane & 15, khi = lane >> 4;
    #pragma unroll
    for (int rfi = 0; rfi < 2; ++rfi)
        #pragma unroll
        for (int cfi = 0; cfi < 2; ++cfi)
            #pragma unroll
            for (int r = 0; r < 4; ++r) {
                int row = wrg*32 + rfi*16 + khi*4 + r;
                int col = nb*64 + wcg*32 + cfi*16 + rlo;
                outp[(m0 + row) * 256 + col] = acc[rfi][cfi][r] + a.ob1[col];
            }
}

// ---------------- persistent cooperative kernel ----------------
__global__ __launch_bounds__(256) void k_persist(PArgs a) {
    extern __shared__ char smem[];
    cg::grid_group grid = cg::this_grid();
    const int bid = blockIdx.x, tid = threadIdx.x;

    for (int L = -1; L <= TT; ++L) {
        for (int task = bid; task < 448; task += 256)
            phaseA_task(smem, tid, task, L, a);
        grid.sync();
        phaseB_item(bid * 256 + tid, L, a);
        grid.sync();
        if (L >= a.R && (L % a.R) == 0) {
            int c = L / a.R - 1;
            int nt1 = a.R * 2 * 16;
            for (int task = bid; task < nt1; task += 256)
                head1_work(smem, tid, task >> 4, task & 15, a);
            grid.sync();
            int nt2 = a.R * 2 * 4;
            float* ob = a.out + (size_t)c * a.R * BB * 256;
            for (int task = bid; task < nt2; task += 256)
                head2_work(smem, tid, task >> 2, task & 3, a, ob);
            grid.sync();
        }
    }
}

// ---------------- fallback (non-cooperative) kernels ----------------
__global__ __launch_bounds__(256) void k_fA(PArgs a, int L) {
    extern __shared__ char smem[];
    phaseA_task(smem, threadIdx.x, blockIdx.x, L, a);
}
__global__ __launch_bounds__(256) void k_fB(PArgs a, int L) {
    phaseB_item(blockIdx.x * 256 + threadIdx.x, L, a);
}
__global__ __launch_bounds__(256) void k_fH1(PArgs a) {
    extern __shared__ char smem[];
    head1_work(smem, threadIdx.x, blockIdx.y, blockIdx.x, a);
}
__global__ __launch_bounds__(256) void k_fH2(PArgs a, float* outp) {
    extern __shared__ char smem[];
    head2_work(smem, threadIdx.x, blockIdx.y, blockIdx.x, a, outp);
}

// ---------------- host ----------------
extern "C" void kernel_launch(void* const* d_in, const int* in_sizes, int n_in,
                              void* d_out, int out_size, void* d_ws, size_t ws_size,
                              hipStream_t stream)
{
    (void)in_sizes; (void)n_in; (void)out_size;
    const float* inputs = (const float*)d_in[0];
    const float* embW   = (const float*)d_in[1];
    const float* W0     = (const float*)d_in[2];
    const float* b0     = (const float*)d_in[3];
    const float* W1     = (const float*)d_in[4];
    const float* b1     = (const float*)d_in[5];
    const float* oW0    = (const float*)d_in[6];
    const float* ob0    = (const float*)d_in[7];
    const float* oW1    = (const float*)d_in[8];
    const float* ob1    = (const float*)d_in[9];
    float* out = (float*)d_out;

    char* base = (char*)d_ws;
    size_t off = 0;
    auto take = [&](size_t n) -> char* {
        size_t a = (off + 255) & ~(size_t)255;
        char* r = base + a;
        off = a + n;
        return r;
    };

    u16* WFh = (u16*)take(4096ull * KPWF * 2);
    u16* WFl = (u16*)take(4096ull * KPWF * 2);
    u16* W0h = (u16*)take(4096ull * 1024 * 2);
    u16* W0l = (u16*)take(4096ull * 1024 * 2);
    u16* W1h = (u16*)take(4096ull * 2048 * 2);
    u16* W1l = (u16*)take(4096ull * 2048 * 2);
    u16* oWAh = (u16*)take(1024ull * 1024 * 2);
    u16* oWAl = (u16*)take(1024ull * 1024 * 2);
    u16* oWBh = (u16*)take(256ull * 1024 * 2);
    u16* oWBl = (u16*)take(256ull * 1024 * 2);
    float* WFfold = (float*)take(259ull * 4096 * 4);
    float* Sv = (float*)take(4096 * 4);
    float* SG = (float*)take((size_t)TT * BB * 4);
    float* Zin = (float*)take(2ull * BB * 4096 * 4);
    float* P0  = (float*)take(2ull * BB * 4096 * 4);
    float* P1  = (float*)take(4ull * BB * 4096 * 4);
    u16* h0h0 = (u16*)take((size_t)BB * 1024 * 2);
    u16* h0l0 = (u16*)take((size_t)BB * 1024 * 2);
    u16* h0h1 = (u16*)take((size_t)BB * 1024 * 2);
    u16* h0l1 = (u16*)take((size_t)BB * 1024 * 2);
    float* c0 = (float*)take((size_t)BB * 1024 * 4);
    float* c1 = (float*)take((size_t)BB * 1024 * 4);

    size_t avail = (ws_size > off + (1u << 20)) ? (ws_size - off - (1u << 20)) : 0;
    int R = 512;
    while (R > 2 && (size_t)R * (BB * 1024ull * 2 * 4) > avail) R >>= 1;
    u16* ringh = (u16*)take((size_t)R * BB * 1024 * 2);
    u16* ringl = (u16*)take((size_t)R * BB * 1024 * 2);
    u16* hsh   = (u16*)take((size_t)R * BB * 1024 * 2);
    u16* hsl   = (u16*)take((size_t)R * BB * 1024 * 2);

    // -------- prep --------
    k_fold<<<dim3(16, 259), 256, 0, stream>>>(embW, W0, WFfold);
    k_S<<<16, 256, 0, stream>>>(W0, Sv);
    k_sgn<<<256, 256, 0, stream>>>(inputs, SG);
    k_split<<<dim3(2, 4096), 256, 0, stream>>>(WFfold, 4096, 259, KPWF, 1, WFh, WFl);
    k_split<<<dim3(4, 4096), 256, 0, stream>>>(W0 + 640ull * 4096, 4096, 1024, 1024, 1, W0h, W0l);
    k_split<<<dim3(8, 4096), 256, 0, stream>>>(W1, 4096, 2048, 2048, 1, W1h, W1l);
    k_split<<<dim3(4, 1024), 256, 0, stream>>>(oW0, 1024, 1024, 1024, 0, oWAh, oWAl);
    k_split<<<dim3(4, 256), 256, 0, stream>>>(oW1, 256, 1024, 1024, 0, oWBh, oWBl);
    k_zero<<<64, 256, 0, stream>>>(c0, BB * 1024);
    k_zero<<<64, 256, 0, stream>>>(c1, BB * 1024);
    k_zero<<<32, 256, 0, stream>>>((float*)h0h1, BB * 1024 / 2);
    k_zero<<<32, 256, 0, stream>>>((float*)h0l1, BB * 1024 / 2);
    k_zero<<<32, 256, 0, stream>>>((float*)(ringh + (size_t)(R - 1) * BB * 1024), BB * 1024 / 2);
    k_zero<<<32, 256, 0, stream>>>((float*)(ringl + (size_t)(R - 1) * BB * 1024), BB * 1024 / 2);

    PArgs pa;
    pa.inp = inputs; pa.Sv = Sv; pa.SG = SG; pa.b0 = b0; pa.b1 = b1; pa.ob0 = ob0; pa.ob1 = ob1;
    pa.WFh = WFh; pa.WFl = WFl; pa.W0h = W0h; pa.W0l = W0l; pa.W1h = W1h; pa.W1l = W1l;
    pa.oWAh = oWAh; pa.oWAl = oWAl; pa.oWBh = oWBh; pa.oWBl = oWBl;
    pa.h0h0 = h0h0; pa.h0l0 = h0l0; pa.h0h1 = h0h1; pa.h0l1 = h0l1;
    pa.ringh = ringh; pa.ringl = ringl; pa.hsh = hsh; pa.hsl = hsl;
    pa.P0 = P0; pa.P1 = P1; pa.Zin = Zin; pa.c0 = c0; pa.c1 = c1;
    pa.out = out; pa.R = R;

    // -------- one cooperative launch; fallback to per-step loop if rejected --------
    void* params[] = { &pa };
    hipError_t err = hipLaunchCooperativeKernel((void*)k_persist, dim3(256), dim3(256),
                                                params, LDS_P, stream);
    if (err != hipSuccess) {
        (void)hipGetLastError();   // clear sticky error
        for (int L = -1; L <= TT; ++L) {
            k_fA<<<448, 256, LDS_P, stream>>>(pa, L);
            k_fB<<<64, 256, 0, stream>>>(pa, L);
            if (L >= R && (L % R) == 0) {
                int c = L / R - 1;
                k_fH1<<<dim3(16, R * 2), 256, LDS_H, stream>>>(pa);
                k_fH2<<<dim3(4, R * 2), 256, LDS_H, stream>>>(pa, out + (size_t)c * R * BB * 256);
            }
        }
    }
}

// Round 13
// 15279.080 us; speedup vs baseline: 4.0118x; 4.0118x over previous
//
#include <hip/hip_runtime.h>
#include <hip/hip_bf16.h>
#include <math.h>

typedef unsigned short u16;
typedef short short8v __attribute__((ext_vector_type(8)));
typedef float f32x4 __attribute__((ext_vector_type(4)));

#define TT 512
#define BB 128
#define IND 259
#define KPWF 384

// LDS: per buffer (M=64): A_hi[64][80] A_lo[64][80] B_hi[NC][80]  (W-lo dropped)
// NC=64: BUFB = 10240 + 5120 = 15360; double-buffered = 30720
#define LDS_BYTES 30720

__device__ __forceinline__ u16 f2bf(float x) {
    __hip_bfloat16 h = __float2bfloat16(x);
    return *reinterpret_cast<u16*>(&h);
}
__device__ __forceinline__ float bf2f(u16 u) {
    unsigned v = ((unsigned)u) << 16;
    return __uint_as_float(v);
}
__device__ __forceinline__ void splitbf(float x, u16& hi, u16& lo) {
    hi = f2bf(x);
    lo = f2bf(x - bf2f(hi));
}

// ---------------- small prep kernels ----------------
__global__ __launch_bounds__(256) void k_zero(float* __restrict__ p, int n) {
    int i = blockIdx.x * 256 + threadIdx.x;
    int stride = gridDim.x * 256;
    for (; i < n; i += stride) p[i] = 0.f;
}

__global__ __launch_bounds__(256) void k_fold(const float* __restrict__ embW,
                                              const float* __restrict__ W0,
                                              float* __restrict__ WF) {
    int j = blockIdx.x * 256 + threadIdx.x;
    int i = blockIdx.y;
    float acc = 0.f;
    for (int e = 0; e < 512; ++e)
        acc += embW[i * 512 + e] * W0[(size_t)e * 4096 + j];
    WF[(size_t)i * 4096 + j] = acc;
}

__global__ __launch_bounds__(256) void k_S(const float* __restrict__ W0, float* __restrict__ S) {
    int j = blockIdx.x * 256 + threadIdx.x;
    float acc = 0.f;
    for (int r = 0; r < 128; ++r)
        acc += W0[(size_t)(512 + r) * 4096 + j];
    S[j] = acc;
}

__global__ __launch_bounds__(256) void k_sgn(const float* __restrict__ inp, float* __restrict__ sgn) {
    int i = blockIdx.x * 256 + threadIdx.x;
    float f0 = inp[(size_t)i * IND + 256];
    float f1 = inp[(size_t)i * IND + 257];
    sgn[i] = (f0 == 1.0f && f1 == 0.0f) ? 1.0f : -1.0f;
}

// Transpose + bf16 split (+ optional gate-permute). Weights use hi plane only now,
// but lo is still produced (activations and any future use); cost is prep-only.
__global__ __launch_bounds__(256) void k_split(const float* __restrict__ src, int srcStride,
                                               int K, int Kpad, int perm,
                                               u16* __restrict__ hi, u16* __restrict__ lo) {
    int col = blockIdx.y;
    int k = blockIdx.x * 256 + threadIdx.x;
    if (k >= Kpad) return;
    int j = col;
    if (perm) {
        int c = col & 15, g = (col >> 4) & 3, hs = col >> 6;
        j = g * 1024 + hs * 16 + c;
    }
    float v = (k < K) ? src[(size_t)k * srcStride + j] : 0.f;
    u16 h, l; splitbf(v, h, l);
    hi[(size_t)col * Kpad + k] = h;
    lo[(size_t)col * Kpad + k] = l;
}

// ---------------- split-A bf16 MFMA GEMM core (M=64, BK=32, 256 thr, 4 waves) ----
// A kept as hi/lo (2 MFMA terms: Ah*Bh + Al*Bh); W-lo plane dropped (halves
// weight streaming, the PMC-identified binder). R6-proven sync structure.
template<int NC, int AMODE>
__device__ __forceinline__ void gemm_core(
    char* smem, int tid,
    const u16* Ah0, const u16* Al0,      // AMODE0: bf16 hi/lo A (pre-offset by m0), lda=1024
    const u16* Ah1, const u16* Al1,      // A source for tiles >= phsw (cell1)
    int phsw,                            // in 32-K tile units
    const float* Af,                     // AMODE1: fp32 A (pre-offset), lda=IND, guard k<IND
    const u16* Bh, int ldb,              // weight hi plane only
    int bmode, int bhalf,                // bmode1: gate-chunk col map (8-col chunks)
    int nkt,
    f32x4 (&acc)[2][NC/32])
{
    constexpr int APL  = 64 * 80;                // 5120 bytes per A plane
    constexpr int BPL  = NC * 80;
    constexpr int BUFB = 2 * APL + BPL;
    const int lane = tid & 63, wid = tid >> 6;
    const int wrg = wid >> 1, wcg = wid & 1;
    const int rlo = lane & 15, khi = lane >> 4;

    // staging maps (256 threads)
    const int srow = tid >> 2;           // 0..63
    const int sk8  = (tid & 3) * 8;      // 0,8,16,24
    int bcol, bq;
    if (NC == 64) { bcol = tid >> 2; bq = tid & 3; }   // 4 thr/col x 8 elems (16B)
    else          { bcol = tid >> 3; bq = tid & 7; }   // 8 thr/col x 4 elems (8B)
    int bcg = bcol;
    if (bmode) bcg = ((bcol >> 3) * 16) + bhalf * 8 + (bcol & 7);

    uint4 ra0, ra1, rb4;
    uint2 rb2;
    float rf[8];

    auto LOADF = [&](int tile) {
        if constexpr (AMODE == 0) {
            const u16* pAh = Ah0; const u16* pAl = Al0; int kk = tile * 32;
            if (tile >= phsw) { pAh = Ah1; pAl = Al1; kk = (tile - phsw) * 32; }
            ra0 = *(const uint4*)(pAh + (size_t)srow * 1024 + kk + sk8);
            ra1 = *(const uint4*)(pAl + (size_t)srow * 1024 + kk + sk8);
        } else {
            const float* sa = Af + (size_t)srow * IND;
            int k0 = tile * 32 + sk8;
            #pragma unroll
            for (int j = 0; j < 8; ++j) rf[j] = (k0 + j < IND) ? sa[k0 + j] : 0.f;
        }
        if constexpr (NC == 64) {
            rb4 = *(const uint4*)(Bh + (size_t)bcg * ldb + tile * 32 + bq * 8);
        } else {
            rb2 = *(const uint2*)(Bh + (size_t)bcg * ldb + tile * 32 + bq * 4);
        }
    };
    auto WRITEF = [&](int tile) {
        char* buf = smem + (tile & 1) * BUFB;
        char* d = buf + srow * 80 + sk8 * 2;
        if constexpr (AMODE == 0) {
            *(uint4*)d = ra0;
            *(uint4*)(d + APL) = ra1;
        } else {
            alignas(16) u16 hb[8], lb[8];
            #pragma unroll
            for (int j = 0; j < 8; ++j) splitbf(rf[j], hb[j], lb[j]);
            *(uint4*)d = *(const uint4*)hb;
            *(uint4*)(d + APL) = *(const uint4*)lb;
        }
        char* e = buf + 2 * APL + bcol * 80;
        if constexpr (NC == 64) {
            *(uint4*)(e + bq * 16) = rb4;
        } else {
            *(uint2*)(e + bq * 8) = rb2;
        }
    };
    auto COMPUTEF = [&](int kt) {
        const char* buf = smem + (kt & 1) * BUFB;
        short8v ah[2], al[2], bh[NC/32];
        #pragma unroll
        for (int rfi = 0; rfi < 2; ++rfi) {
            int row = wrg * 32 + rfi * 16 + rlo;
            const char* p = buf + row * 80 + khi * 16;
            ah[rfi] = *(const short8v*)p;
            al[rfi] = *(const short8v*)(p + APL);
        }
        #pragma unroll
        for (int cfi = 0; cfi < NC/32; ++cfi) {
            int col = wcg * (NC/2) + cfi * 16 + rlo;
            bh[cfi] = *(const short8v*)(buf + 2 * APL + col * 80 + khi * 16);
        }
        #pragma unroll
        for (int rfi = 0; rfi < 2; ++rfi)
            #pragma unroll
            for (int cfi = 0; cfi < NC/32; ++cfi) {
                acc[rfi][cfi] = __builtin_amdgcn_mfma_f32_16x16x32_bf16(ah[rfi], bh[cfi], acc[rfi][cfi], 0, 0, 0);
                acc[rfi][cfi] = __builtin_amdgcn_mfma_f32_16x16x32_bf16(al[rfi], bh[cfi], acc[rfi][cfi], 0, 0, 0);
            }
    };

    LOADF(0); WRITEF(0); __syncthreads();
    for (int kt = 0; kt < nkt; ++kt) {
        if (kt + 1 < nkt) LOADF(kt + 1);
        COMPUTEF(kt);
        if (kt + 1 < nkt) WRITEF(kt + 1);
        __syncthreads();
    }
}

template<int NC>
__device__ __forceinline__ void store_zs(char* smem, int tid, f32x4 (&acc)[2][NC/32], int ncp) {
    float* zs = (float*)smem;
    const int lane = tid & 63, wid = tid >> 6;
    const int wrg = wid >> 1, wcg = wid & 1;
    const int rlo = lane & 15, khi = lane >> 4;
    #pragma unroll
    for (int rfi = 0; rfi < 2; ++rfi)
        #pragma unroll
        for (int cfi = 0; cfi < NC/32; ++cfi)
            #pragma unroll
            for (int r = 0; r < 4; ++r)
                zs[(wrg*32 + rfi*16 + khi*4 + r) * ncp + wcg*(NC/2) + cfi*16 + rlo] = acc[rfi][cfi][r];
}

// ---------------- merged per-step kernel (512 wgs = 2 blocks/CU) ----------------
struct SArgs {
    const float *inp, *Sv, *SG, *b0, *b1;
    const u16 *WFh, *W0h, *W1h;
    u16 *h0h0, *h0l0, *h0h1, *h0l1;
    u16 *ringh, *ringl;
    float *Zin, *c0, *c1;
    int R, t;
};

__global__ __launch_bounds__(256) void k_step(SArgs a) {
    extern __shared__ char smem[];
    const int bid = blockIdx.x, tid = threadIdx.x;
    const int t = a.t;

    if (bid < 128) {
        // ---------- cell0 step t: z = h0[t-1] @ W0h + Zin[t] + sgn*S + b0 ----------
        if (t < 0 || t >= TT) return;
        const int mb = bid >> 6, hs = bid & 63;
        const int m0 = mb * 64;
        f32x4 acc[2][2];
        #pragma unroll
        for (int i = 0; i < 2; ++i) { acc[i][0] = (f32x4)0.f; acc[i][1] = (f32x4)0.f; }
        const u16* Ah = (((t - 1) & 1) ? a.h0h1 : a.h0h0) + (size_t)m0 * 1024;
        const u16* Al = (((t - 1) & 1) ? a.h0l1 : a.h0l0) + (size_t)m0 * 1024;
        gemm_core<64,0>(smem, tid, Ah, Al, Ah, Al, 99, nullptr,
                        a.W0h + (size_t)hs*64*1024, 1024,
                        0, 0, 32, acc);
        store_zs<64>(smem, tid, acc, 68);
        __syncthreads();
        float* zs = (float*)smem;
        const float* zin = a.Zin + (size_t)(t & 1) * BB * 4096;
        u16* hoh = ((t & 1) ? a.h0h1 : a.h0h0);
        u16* hol = ((t & 1) ? a.h0l1 : a.h0l0);
        #pragma unroll
        for (int i = 0; i < 4; ++i) {
            int q = tid + 256 * i;              // 1024 items: 64 rows x 16 cols
            int row = q >> 4, c16 = q & 15;
            int grow = m0 + row;
            int hid = hs * 16 + c16;
            float sg = a.SG[(size_t)t * BB + grow];
            const float* zr = zs + row * 68;
            const float* zn = zin + (size_t)grow * 4096 + hs * 64;
            float zF = zr[c16]      + zn[c16]      + sg * a.Sv[hid]        + a.b0[hid];
            float zI = zr[16 + c16] + zn[16 + c16] + sg * a.Sv[1024 + hid] + a.b0[1024 + hid];
            float zO = zr[32 + c16] + zn[32 + c16] + sg * a.Sv[2048 + hid] + a.b0[2048 + hid];
            float zG = zr[48 + c16] + zn[48 + c16] + sg * a.Sv[3072 + hid] + a.b0[3072 + hid];
            float f = 1.f / (1.f + expf(-zF));
            float ii = 1.f / (1.f + expf(-zI));
            float o = 1.f / (1.f + expf(-zO));
            float g = tanhf(zG);
            size_t ci = (size_t)grow * 1024 + hid;
            float cn = f * a.c0[ci] + ii * g;
            a.c0[ci] = cn;
            float h = o * tanhf(cn);
            u16 hh, hl; splitbf(h, hh, hl);
            hoh[ci] = hh; hol[ci] = hl;
        }
    } else if (bid < 384) {
        // ---------- cell1 step tau=t-1: z = [h0[tau], h1[tau-1]] @ W1 + b1 ----------
        const int tau = t - 1;
        if (tau < 0 || tau >= TT) return;
        const int bb = bid - 128;
        const int mb = bb >> 7, sub = bb & 127;
        const int hs = sub >> 1, half = sub & 1;
        const int m0 = mb * 64;
        f32x4 acc[2][1];
        #pragma unroll
        for (int i = 0; i < 2; ++i) acc[i][0] = (f32x4)0.f;
        const u16* A0h = (((tau & 1) ? a.h0h1 : a.h0h0)) + (size_t)m0 * 1024;
        const u16* A0l = (((tau & 1) ? a.h0l1 : a.h0l0)) + (size_t)m0 * 1024;
        int slotr = (tau - 1 + a.R) % a.R;
        const u16* A1h = a.ringh + (size_t)slotr * BB * 1024 + (size_t)m0 * 1024;
        const u16* A1l = a.ringl + (size_t)slotr * BB * 1024 + (size_t)m0 * 1024;
        gemm_core<32,0>(smem, tid, A0h, A0l, A1h, A1l, 32, nullptr,
                        a.W1h + (size_t)hs*64*2048, 2048,
                        1, half, 64, acc);
        store_zs<32>(smem, tid, acc, 36);
        __syncthreads();
        float* zs = (float*)smem;
        int slotw = tau % a.R;
        u16* rh = a.ringh + (size_t)slotw * BB * 1024;
        u16* rl = a.ringl + (size_t)slotw * BB * 1024;
        #pragma unroll
        for (int i = 0; i < 2; ++i) {
            int q = tid + 256 * i;              // 512 items: 64 rows x 8 cols
            int row = q >> 3, c8 = q & 7;
            int grow = m0 + row;
            int hid = hs * 16 + half * 8 + c8;
            const float* zr = zs + row * 36;
            float zF = zr[c8]      + a.b1[hid];
            float zI = zr[8 + c8]  + a.b1[1024 + hid];
            float zO = zr[16 + c8] + a.b1[2048 + hid];
            float zG = zr[24 + c8] + a.b1[3072 + hid];
            float f = 1.f / (1.f + expf(-zF));
            float ii = 1.f / (1.f + expf(-zI));
            float o = 1.f / (1.f + expf(-zO));
            float g = tanhf(zG);
            size_t ci = (size_t)grow * 1024 + hid;
            float cn = f * a.c1[ci] + ii * g;
            a.c1[ci] = cn;
            float h = o * tanhf(cn);
            u16 hh, hl; splitbf(h, hh, hl);
            rh[ci] = hh; rl[ci] = hl;
        }
    } else {
        // ---------- Zin for step t+1: Zin = inp[t+1] @ WFt ----------
        const int tz = t + 1;
        if (tz < 0 || tz >= TT) return;
        const int zb = bid - 384;
        const int mb = zb >> 6, cwg = zb & 63;
        const int m0 = mb * 64;
        const int col0 = cwg * 64;
        f32x4 acc[2][2];
        #pragma unroll
        for (int i = 0; i < 2; ++i) { acc[i][0] = (f32x4)0.f; acc[i][1] = (f32x4)0.f; }
        const float* Af = a.inp + (size_t)tz * BB * IND + (size_t)m0 * IND;
        gemm_core<64,1>(smem, tid, nullptr, nullptr, nullptr, nullptr, 999, Af,
                        a.WFh + (size_t)col0 * KPWF, KPWF,
                        0, 0, KPWF / 32, acc);
        float* zo = a.Zin + (size_t)(tz & 1) * BB * 4096;
        const int lane = tid & 63, wid = tid >> 6;
        const int wrg = wid >> 1, wcg = wid & 1;
        const int rlo = lane & 15, khi = lane >> 4;
        #pragma unroll
        for (int rfi = 0; rfi < 2; ++rfi)
            #pragma unroll
            for (int cfi = 0; cfi < 2; ++cfi)
                #pragma unroll
                for (int r = 0; r < 4; ++r)
                    zo[(size_t)(m0 + wrg*32 + rfi*16 + khi*4 + r) * 4096 + col0 + wcg*32 + cfi*16 + rlo] = acc[rfi][cfi][r];
    }
}

// ---------------- head ----------------
__global__ __launch_bounds__(256) void k_head1(const u16* __restrict__ ringh, const u16* __restrict__ ringl,
                                               const u16* __restrict__ Wh,
                                               const float* __restrict__ bias,
                                               u16* __restrict__ hsh, u16* __restrict__ hsl) {
    extern __shared__ char smem[];
    const int tid = threadIdx.x;
    const int nb = blockIdx.x, mb = blockIdx.y;
    const size_t m0 = (size_t)mb * 64;
    f32x4 acc[2][2];
    #pragma unroll
    for (int i = 0; i < 2; ++i) { acc[i][0] = (f32x4)0.f; acc[i][1] = (f32x4)0.f; }
    const u16* Ah = ringh + m0 * 1024;
    const u16* Al = ringl + m0 * 1024;
    gemm_core<64,0>(smem, tid, Ah, Al, Ah, Al, 99, nullptr,
                    Wh + (size_t)nb*64*1024, 1024,
                    0, 0, 32, acc);
    const int lane = tid & 63, wid = tid >> 6;
    const int wrg = wid >> 1, wcg = wid & 1;
    const int rlo = lane & 15, khi = lane >> 4;
    #pragma unroll
    for (int rfi = 0; rfi < 2; ++rfi)
        #pragma unroll
        for (int cfi = 0; cfi < 2; ++cfi)
            #pragma unroll
            for (int r = 0; r < 4; ++r) {
                int row = wrg*32 + rfi*16 + khi*4 + r;
                int col = nb*64 + wcg*32 + cfi*16 + rlo;
                float v = acc[rfi][cfi][r] + bias[col];
                v = fmaxf(v, 0.f);
                u16 hh, hl; splitbf(v, hh, hl);
                size_t o = (m0 + row) * 1024 + col;
                hsh[o] = hh; hsl[o] = hl;
            }
}

__global__ __launch_bounds__(256) void k_head2(const u16* __restrict__ hsh, const u16* __restrict__ hsl,
                                               const u16* __restrict__ Wh,
                                               const float* __restrict__ bias,
                                               float* __restrict__ outp) {
    extern __shared__ char smem[];
    const int tid = threadIdx.x;
    const int nb = blockIdx.x, mb = blockIdx.y;
    const size_t m0 = (size_t)mb * 64;
    f32x4 acc[2][2];
    #pragma unroll
    for (int i = 0; i < 2; ++i) { acc[i][0] = (f32x4)0.f; acc[i][1] = (f32x4)0.f; }
    const u16* Ah = hsh + m0 * 1024;
    const u16* Al = hsl + m0 * 1024;
    gemm_core<64,0>(smem, tid, Ah, Al, Ah, Al, 99, nullptr,
                    Wh + (size_t)nb*64*1024, 1024,
                    0, 0, 32, acc);
    const int lane = tid & 63, wid = tid >> 6;
    const int wrg = wid >> 1, wcg = wid & 1;
    const int rlo = lane & 15, khi = lane >> 4;
    #pragma unroll
    for (int rfi = 0; rfi < 2; ++rfi)
        #pragma unroll
        for (int cfi = 0; cfi < 2; ++cfi)
            #pragma unroll
            for (int r = 0; r < 4; ++r) {
                int row = wrg*32 + rfi*16 + khi*4 + r;
                int col = nb*64 + wcg*32 + cfi*16 + rlo;
                outp[(m0 + row) * 256 + col] = acc[rfi][cfi][r] + bias[col];
            }
}

// ---------------- host ----------------
extern "C" void kernel_launch(void* const* d_in, const int* in_sizes, int n_in,
                              void* d_out, int out_size, void* d_ws, size_t ws_size,
                              hipStream_t stream)
{
    (void)in_sizes; (void)n_in; (void)out_size;
    const float* inputs = (const float*)d_in[0];
    const float* embW   = (const float*)d_in[1];
    const float* W0     = (const float*)d_in[2];
    const float* b0     = (const float*)d_in[3];
    const float* W1     = (const float*)d_in[4];
    const float* b1     = (const float*)d_in[5];
    const float* oW0    = (const float*)d_in[6];
    const float* ob0    = (const float*)d_in[7];
    const float* oW1    = (const float*)d_in[8];
    const float* ob1    = (const float*)d_in[9];
    float* out = (float*)d_out;

    char* base = (char*)d_ws;
    size_t off = 0;
    auto take = [&](size_t n) -> char* {
        size_t a = (off + 255) & ~(size_t)255;
        char* r = base + a;
        off = a + n;
        return r;
    };

    u16* WFh = (u16*)take(4096ull * KPWF * 2);
    u16* WFl = (u16*)take(4096ull * KPWF * 2);
    u16* W0h = (u16*)take(4096ull * 1024 * 2);
    u16* W0l = (u16*)take(4096ull * 1024 * 2);
    u16* W1h = (u16*)take(4096ull * 2048 * 2);
    u16* W1l = (u16*)take(4096ull * 2048 * 2);
    u16* oWAh = (u16*)take(1024ull * 1024 * 2);
    u16* oWAl = (u16*)take(1024ull * 1024 * 2);
    u16* oWBh = (u16*)take(256ull * 1024 * 2);
    u16* oWBl = (u16*)take(256ull * 1024 * 2);
    float* WFfold = (float*)take(259ull * 4096 * 4);
    float* Sv = (float*)take(4096 * 4);
    float* SG = (float*)take((size_t)TT * BB * 4);
    float* Zin = (float*)take(2ull * BB * 4096 * 4);
    u16* h0h0 = (u16*)take((size_t)BB * 1024 * 2);
    u16* h0l0 = (u16*)take((size_t)BB * 1024 * 2);
    u16* h0h1 = (u16*)take((size_t)BB * 1024 * 2);
    u16* h0l1 = (u16*)take((size_t)BB * 1024 * 2);
    float* c0 = (float*)take((size_t)BB * 1024 * 4);
    float* c1 = (float*)take((size_t)BB * 1024 * 4);

    size_t avail = (ws_size > off + (1u << 20)) ? (ws_size - off - (1u << 20)) : 0;
    int R = 512;
    while (R > 2 && (size_t)R * (BB * 1024ull * 2 * 4) > avail) R >>= 1;
    u16* ringh = (u16*)take((size_t)R * BB * 1024 * 2);
    u16* ringl = (u16*)take((size_t)R * BB * 1024 * 2);
    u16* hsh   = (u16*)take((size_t)R * BB * 1024 * 2);
    u16* hsl   = (u16*)take((size_t)R * BB * 1024 * 2);

    // -------- prep --------
    k_fold<<<dim3(16, 259), 256, 0, stream>>>(embW, W0, WFfold);
    k_S<<<16, 256, 0, stream>>>(W0, Sv);
    k_sgn<<<256, 256, 0, stream>>>(inputs, SG);
    k_split<<<dim3(2, 4096), 256, 0, stream>>>(WFfold, 4096, 259, KPWF, 1, WFh, WFl);
    k_split<<<dim3(4, 4096), 256, 0, stream>>>(W0 + 640ull * 4096, 4096, 1024, 1024, 1, W0h, W0l);
    k_split<<<dim3(8, 4096), 256, 0, stream>>>(W1, 4096, 2048, 2048, 1, W1h, W1l);
    k_split<<<dim3(4, 1024), 256, 0, stream>>>(oW0, 1024, 1024, 1024, 0, oWAh, oWAl);
    k_split<<<dim3(4, 256), 256, 0, stream>>>(oW1, 256, 1024, 1024, 0, oWBh, oWBl);
    k_zero<<<64, 256, 0, stream>>>(c0, BB * 1024);
    k_zero<<<64, 256, 0, stream>>>(c1, BB * 1024);
    k_zero<<<32, 256, 0, stream>>>((float*)h0h1, BB * 1024 / 2);
    k_zero<<<32, 256, 0, stream>>>((float*)h0l1, BB * 1024 / 2);
    k_zero<<<32, 256, 0, stream>>>((float*)(ringh + (size_t)(R - 1) * BB * 1024), BB * 1024 / 2);
    k_zero<<<32, 256, 0, stream>>>((float*)(ringl + (size_t)(R - 1) * BB * 1024), BB * 1024 / 2);

    // -------- serial recurrence (merged cell0 || cell1 || Zin), 512 wgs/step --------
    SArgs a;
    a.inp = inputs; a.Sv = Sv; a.SG = SG; a.b0 = b0; a.b1 = b1;
    a.WFh = WFh; a.W0h = W0h; a.W1h = W1h;
    a.h0h0 = h0h0; a.h0l0 = h0l0; a.h0h1 = h0h1; a.h0l1 = h0l1;
    a.ringh = ringh; a.ringl = ringl;
    a.Zin = Zin; a.c0 = c0; a.c1 = c1;
    a.R = R;

    for (int L = -1; L <= TT; ++L) {
        a.t = L;
        k_step<<<512, 256, LDS_BYTES, stream>>>(a);
        if (L >= 1 && (L % R) == 0) {
            int c = L / R - 1;
            k_head1<<<dim3(16, R * 2), 256, LDS_BYTES, stream>>>(ringh, ringl, oWAh, ob0, hsh, hsl);
            k_head2<<<dim3(4, R * 2), 256, LDS_BYTES, stream>>>(hsh, hsl, oWBh, ob1,
                                                                out + (size_t)c * R * BB * 256);
        }
    }
}